// Round 6
// baseline (648.476 us; speedup 1.0000x reference)
//
#include <hip/hip_runtime.h>
#include <hip/hip_bf16.h>

typedef __attribute__((ext_vector_type(8))) short bf16x8;
typedef __attribute__((ext_vector_type(4))) float f32x4;

#define HID 512
#define NB 32
#define SEQL 4096
#define NKC 16          // 512/32 k-chunks
#define BMR 32          // rows per block
#define NBLK 4096       // 131072 rows / 32
#define APAD 8
#define AW (HID + APAD) // 520 shorts; row stride 1040 B (16B-aligned, odd multiple of 16)

// workspace layout (bytes)
#define WS_BP    0              // packed bf16 W_enc: 512 KB
#define WS_DPROJ (512*1024)     // fp32 32x512: 64 KB
#define WS_SUM   (576*1024)     // fp32 32: 128 B

__device__ __forceinline__ short f2bf(float f) {
    unsigned u = __float_as_uint(f);
    unsigned r = (u + 0x7fffu + ((u >> 16) & 1u)) >> 16;   // RNE
    return (short)r;
}

__device__ __forceinline__ float fast_tanh(float x) {
    float e = __expf(2.0f * x);
    float r = __builtin_amdgcn_rcpf(e + 1.0f);
    return 1.0f - 2.0f * r;
}

// ---------------------------------------------------------------------------
// K_pre: (a) W_enc pack fp32->bf16 B-frag layout [blk 0..127],
// (b) dproj GEMV 8-way h-parallel [blk 128..639], (c) zero ctx+sumacc [640..703]
// ---------------------------------------------------------------------------
__global__ void k_pre(const float* __restrict__ We, short* __restrict__ Bp,
                      const float* __restrict__ dec, const float* __restrict__ Wd,
                      const float* __restrict__ be, const float* __restrict__ bd,
                      float* __restrict__ dproj, float* __restrict__ out,
                      float* __restrict__ sumacc) {
    const int blk = blockIdx.x, t = threadIdx.x;
    if (blk < 128) {
        // Bp[kc][nt][lane][j] = We[kc*32 + (lane>>4)*8 + j][nt*16 + (lane&15)]
        int tid  = blk * 256 + t;
        int lane = tid & 63;
        int nt   = (tid >> 6) & 31;
        int kc   = tid >> 11;
        int k0   = kc * 32 + (lane >> 4) * 8;
        int n    = nt * 16 + (lane & 15);
        bf16x8 v;
#pragma unroll
        for (int j = 0; j < 8; ++j) v[j] = f2bf(We[(size_t)(k0 + j) * HID + n]);
        *(bf16x8*)&Bp[(size_t)tid * 8] = v;
    } else if (blk < 640) {
        __shared__ float red[8][33];
        int bid2 = blk - 128;
        int b  = bid2 >> 4, kg = bid2 & 15;     // 32 batches x 16 k-groups
        int kl = t & 31,    hc = t >> 5;        // 32 k-cols x 8 h-chunks
        int k  = kg * 32 + kl;
        const float* dr = dec + (size_t)b * HID;
        float a = 0.f;
#pragma unroll 8
        for (int j = 0; j < 64; ++j) {
            int h = hc * 64 + j;
            a += dr[h] * Wd[(size_t)h * HID + k];
        }
        red[hc][kl] = a;
        __syncthreads();
        if (hc == 0) {
            float s = be[k] + bd[k];
#pragma unroll
            for (int c = 0; c < 8; ++c) s += red[c][kl];
            dproj[(size_t)b * HID + k] = s;
        }
    } else {
        int bz = blk - 640;
        out[bz * 256 + t] = 0.f;                // zero context region (16384 f32)
        if (bz == 0 && t < NB) sumacc[t] = 0.f;
    }
}

// ---------------------------------------------------------------------------
// K_main: 32-row blocks (4 waves), 4 blocks/CU target.
//  - A-tile 32x512 fp32->bf16 staged to LDS once; ONE barrier.
//  - Wave owns 128 cols; col-group loop (4 x 32 cols): acc[2][2] folded into
//    sp after each group -> max live regs ~90, no spills, 4 waves/SIMD.
//  - fb streamed from L2-resident Bp, register-double-buffered with fa.
//  - Cross-wave score reduce in LDS -> exp -> weights + atomic expsum.
//  - Context partial from global E (L2-hot) -> atomicAdd (R1-proven scheme).
// ---------------------------------------------------------------------------
__global__ __launch_bounds__(256, 4)
void k_main(const float* __restrict__ E, const short* __restrict__ Bp,
            const float* __restrict__ dproj, const float* __restrict__ Wv,
            float* __restrict__ out, float* __restrict__ sumacc) {
    __shared__ short As[BMR][AW];    // 33.3 KB
    __shared__ float sred[4][32];    // per-wave score partials
    __shared__ float pbuf[BMR];
    __shared__ float cred[512];      // context pair-reduce

    const int tid  = threadIdx.x;
    const int wave = tid >> 6, lane = tid & 63;
    const int quad = lane >> 4, l15 = lane & 15;
    const int bid  = blockIdx.x;
    const int row0 = bid * BMR;          // global row = b*4096 + s
    const int b    = bid >> 7;           // 128 blocks per batch

    // ---- stage A-tile: 32x512 fp32 -> bf16 LDS; 16 float4/thread, coalesced ----
    const float4* E4 = (const float4*)E + (size_t)row0 * (HID / 4);
#pragma unroll
    for (int i = 0; i < 16; ++i) {
        int f = i * 256 + tid;           // float4 index in tile
        float4 v = E4[f];
        int row = f >> 7, c4 = f & 127;
        short4 s;
        s.x = f2bf(v.x); s.y = f2bf(v.y); s.z = f2bf(v.z); s.w = f2bf(v.w);
        *(short4*)&As[row][c4 * 4] = s;
    }
    __syncthreads();   // the ONLY barrier before epilogue

    // ---- K-sweep: wave cols [wave*128, +128), col-groups of 32 ----
    const float* dp = dproj + (size_t)b * HID;
    float sp[2][4] = {{0.f,0.f,0.f,0.f},{0.f,0.f,0.f,0.f}};   // [row-tile][g]

#pragma unroll 1
    for (int cg = 0; cg < 4; ++cg) {
        const int ntb = wave * 8 + cg * 2;
        const short* bcg = Bp + ((size_t)ntb * 64 + lane) * 8;  // + kc*16384 + ct*512
        // dv/wv issued now, consumed after the 16-kc chain (latency hidden)
        int col = wave * 128 + cg * 32 + l15;
        float dv0 = dp[col],      wv0 = Wv[col];
        float dv1 = dp[col + 16], wv1 = Wv[col + 16];

        f32x4 acc[2][2];
#pragma unroll
        for (int rt = 0; rt < 2; ++rt)
#pragma unroll
            for (int ct = 0; ct < 2; ++ct) acc[rt][ct] = (f32x4){0.f,0.f,0.f,0.f};

        bf16x8 cfb[2][2], cfa[2][2];
        cfb[0][0] = *(const bf16x8*)(bcg);
        cfb[0][1] = *(const bf16x8*)(bcg + 512);
        cfa[0][0] = *(const bf16x8*)&As[l15][quad * 8];
        cfa[0][1] = *(const bf16x8*)&As[16 + l15][quad * 8];
#pragma unroll
        for (int kc = 0; kc < NKC; ++kc) {
            const int cur = kc & 1, nxt = cur ^ 1;
            if (kc + 1 < NKC) {
                const short* bn = bcg + (size_t)(kc + 1) * 16384;
                cfb[nxt][0] = *(const bf16x8*)(bn);
                cfb[nxt][1] = *(const bf16x8*)(bn + 512);
                cfa[nxt][0] = *(const bf16x8*)&As[l15][(kc + 1) * 32 + quad * 8];
                cfa[nxt][1] = *(const bf16x8*)&As[16 + l15][(kc + 1) * 32 + quad * 8];
            }
#pragma unroll
            for (int rt = 0; rt < 2; ++rt)
#pragma unroll
                for (int ct = 0; ct < 2; ++ct)
                    acc[rt][ct] = __builtin_amdgcn_mfma_f32_16x16x32_bf16(
                        cfa[cur][rt], cfb[cur][ct], acc[rt][ct], 0, 0, 0);
        }
        // fold: rows rt*16 + quad*4 + g ; cols cg*32 + ct*16 + l15
#pragma unroll
        for (int rt = 0; rt < 2; ++rt)
#pragma unroll
            for (int g = 0; g < 4; ++g) {
                sp[rt][g] += fast_tanh(acc[rt][0][g] + dv0) * wv0;
                sp[rt][g] += fast_tanh(acc[rt][1][g] + dv1) * wv1;
            }
    }

    // ---- reduce sp over l15 lanes, publish per-wave partials ----
#pragma unroll
    for (int rt = 0; rt < 2; ++rt)
#pragma unroll
        for (int g = 0; g < 4; ++g) {
            float v = sp[rt][g];
            v += __shfl_xor(v, 1); v += __shfl_xor(v, 2);
            v += __shfl_xor(v, 4); v += __shfl_xor(v, 8);
            sp[rt][g] = v;
        }
    if (l15 == 0) {
#pragma unroll
        for (int rt = 0; rt < 2; ++rt)
#pragma unroll
            for (int g = 0; g < 4; ++g)
                sred[wave][rt * 16 + quad * 4 + g] = sp[rt][g];
    }
    __syncthreads();

    // ---- final scores -> exp -> weights + block expsum ----
    if (tid < 32) {
        float s = sred[0][tid] + sred[1][tid] + sred[2][tid] + sred[3][tid];
        float pv = __expf(s);            // unnormalized; b_v cancels in softmax
        pbuf[tid] = pv;
        out[(size_t)NB * HID + row0 + tid] = pv;
        float t2 = pv;
        t2 += __shfl_xor(t2, 1); t2 += __shfl_xor(t2, 2); t2 += __shfl_xor(t2, 4);
        t2 += __shfl_xor(t2, 8); t2 += __shfl_xor(t2, 16);
        if (tid == 0) atomicAdd(&sumacc[b], t2);
    }
    __syncthreads();

    // ---- context partial: 32 rows x 512 h, E re-read (same-XCD L2-hot) ----
    const int hq = tid & 127, rh = tid >> 7;      // h = hq*4; rows rh*16..+16
    const float4* Eb = (const float4*)E;
    size_t cbase = (size_t)(row0 + rh * 16) * (HID / 4) + hq;
    float4 ca = {0.f, 0.f, 0.f, 0.f};
#pragma unroll 4
    for (int rr = 0; rr < 16; ++rr) {
        float w  = pbuf[rh * 16 + rr];
        float4 e = Eb[cbase + (size_t)rr * (HID / 4)];
        ca.x += w * e.x; ca.y += w * e.y; ca.z += w * e.z; ca.w += w * e.w;
    }
    if (rh == 1) {
        cred[hq] = ca.x; cred[128 + hq] = ca.y;
        cred[256 + hq] = ca.z; cred[384 + hq] = ca.w;
    }
    __syncthreads();
    if (rh == 0) {
        ca.x += cred[hq]; ca.y += cred[128 + hq];
        ca.z += cred[256 + hq]; ca.w += cred[384 + hq];
        float* cg = out + (size_t)b * HID + hq * 4;
        atomicAdd(cg + 0, ca.x); atomicAdd(cg + 1, ca.y);
        atomicAdd(cg + 2, ca.z); atomicAdd(cg + 3, ca.w);
    }
}

// ---------------------------------------------------------------------------
// K_finish: normalize in place: context /= sum, weights /= sum
// ---------------------------------------------------------------------------
__global__ void k_finish(float* __restrict__ out, const float* __restrict__ sumacc) {
    int b = blockIdx.x, t = threadIdx.x;
    float rs = 1.0f / sumacc[b];
    for (int i = t; i < HID; i += 256)
        out[(size_t)b * HID + i] *= rs;
    float* ow = out + (size_t)NB * HID + (size_t)b * SEQL;
    for (int i = t; i < SEQL; i += 256)
        ow[i] *= rs;
}

extern "C" void kernel_launch(void* const* d_in, const int* in_sizes, int n_in,
                              void* d_out, int out_size, void* d_ws, size_t ws_size,
                              hipStream_t stream) {
    const float* E   = (const float*)d_in[0];
    const float* dec = (const float*)d_in[1];
    const float* We  = (const float*)d_in[2];
    const float* be  = (const float*)d_in[3];
    const float* Wd  = (const float*)d_in[4];
    const float* bd  = (const float*)d_in[5];
    const float* Wv  = (const float*)d_in[6];
    // d_in[7] = b_v: uniform shift per score -> cancels in softmax
    float* out = (float*)d_out;
    char*  ws  = (char*)d_ws;
    short* Bp     = (short*)(ws + WS_BP);
    float* dproj  = (float*)(ws + WS_DPROJ);
    float* sumacc = (float*)(ws + WS_SUM);

    k_pre<<<704, 256, 0, stream>>>(We, Bp, dec, Wd, be, bd, dproj, out, sumacc);
    k_main<<<NBLK, 256, 0, stream>>>(E, Bp, dproj, Wv, out, sumacc);
    k_finish<<<NB, 256, 0, stream>>>(out, sumacc);
}

// Round 7
// 449.187 us; speedup vs baseline: 1.4437x; 1.4437x over previous
//
#include <hip/hip_runtime.h>
#include <hip/hip_bf16.h>

typedef __attribute__((ext_vector_type(8))) short bf16x8;
typedef __attribute__((ext_vector_type(4))) float f32x4;

#define HID 512
#define NB 32
#define SEQL 4096
#define BM 64
#define BK 32
#define NKC 16          // 512/32 k-chunks
#define NBLK 2048       // 131072 rows / 64

// workspace layout (bytes)
#define WS_BP    0              // packed bf16 W_enc: 512 KB
#define WS_DPROJ (512*1024)     // fp32 32x512: 64 KB
#define WS_SUM   (576*1024)     // fp32 32: 128 B

__device__ __forceinline__ short f2bf(float f) {
    unsigned u = __float_as_uint(f);
    unsigned r = (u + 0x7fffu + ((u >> 16) & 1u)) >> 16;   // RNE
    return (short)r;
}

__device__ __forceinline__ float fast_tanh(float x) {
    float e = __expf(2.0f * x);
    float r = __builtin_amdgcn_rcpf(e + 1.0f);
    return 1.0f - 2.0f * r;
}

__device__ __forceinline__ void async16(const void* g, void* l) {
    __builtin_amdgcn_global_load_lds((__attribute__((address_space(1))) void*)(g),
                                     (__attribute__((address_space(3))) void*)(l),
                                     16, 0, 0);
}

// ---------------------------------------------------------------------------
// K_pre (R3's measured-faster version): (a) W_enc pack fp32->bf16 B-frag
// layout [blk 0..127], (b) dproj GEMV 8-way h-parallel [blk 128..639],
// (c) zero ctx + sumacc [blk 640..703]
// ---------------------------------------------------------------------------
__global__ void k_pre(const float* __restrict__ We, short* __restrict__ Bp,
                      const float* __restrict__ dec, const float* __restrict__ Wd,
                      const float* __restrict__ be, const float* __restrict__ bd,
                      float* __restrict__ dproj, float* __restrict__ out,
                      float* __restrict__ sumacc) {
    const int blk = blockIdx.x, t = threadIdx.x;
    if (blk < 128) {
        // Bp[kc][nt][lane][j] = We[kc*32 + (lane>>4)*8 + j][nt*16 + (lane&15)]
        int tid  = blk * 256 + t;
        int lane = tid & 63;
        int nt   = (tid >> 6) & 31;
        int kc   = tid >> 11;
        int k0   = kc * 32 + (lane >> 4) * 8;
        int n    = nt * 16 + (lane & 15);
        bf16x8 v;
#pragma unroll
        for (int j = 0; j < 8; ++j) v[j] = f2bf(We[(size_t)(k0 + j) * HID + n]);
        *(bf16x8*)&Bp[(size_t)tid * 8] = v;
    } else if (blk < 640) {
        __shared__ float red[8][33];
        int bid2 = blk - 128;
        int b  = bid2 >> 4, kg = bid2 & 15;     // 32 batches x 16 k-groups
        int kl = t & 31,    hc = t >> 5;        // 32 k-cols x 8 h-chunks
        int k  = kg * 32 + kl;
        const float* dr = dec + (size_t)b * HID;
        float a = 0.f;
#pragma unroll 8
        for (int j = 0; j < 64; ++j) {
            int h = hc * 64 + j;
            a += dr[h] * Wd[(size_t)h * HID + k];
        }
        red[hc][kl] = a;
        __syncthreads();
        if (hc == 0) {
            float s = be[k] + bd[k];
#pragma unroll
            for (int c = 0; c < 8; ++c) s += red[c][kl];
            dproj[(size_t)b * HID + k] = s;
        }
    } else {
        int bz = blk - 640;
        out[bz * 256 + t] = 0.f;                // zero context region (16384 f32)
        if (bz == 0 && t < NB) sumacc[t] = 0.f;
    }
}

// ---------------------------------------------------------------------------
// K_main (R1 verbatim — best measured structure, 177 us):
// 64 rows x 512 cols enc_proj via bf16 MFMA; A greedy-staged fp32->bf16,
// B via async16 (global_load_lds width=16) from L2-resident packed Bp;
// fused tanh*W_v -> score -> p=exp(score) -> partial expsum + partial context.
// ---------------------------------------------------------------------------
__global__ __launch_bounds__(256, 2)
void k_main(const float* __restrict__ E, const short* __restrict__ Bp,
            const float* __restrict__ dproj, const float* __restrict__ Wv,
            float* __restrict__ out, float* __restrict__ sumacc) {
    __shared__ short As[BM][BK + 8];   // 64 x 40 shorts (pad -> 2-way max, free)
    __shared__ short Bs[BK * HID];     // 16384 shorts = 32 KB, packed [nt][lane][8]
    __shared__ float fbuf[640];
    __shared__ float pbuf[BM];

    const int tid  = threadIdx.x;
    const int wave = tid >> 6, lane = tid & 63;
    const int quad = lane >> 4, l15 = lane & 15;
    const int bid  = blockIdx.x;
    const int row0 = bid * BM;           // global row = b*4096 + s
    const int b    = bid >> 6;           // 64 blocks per batch

    f32x4 acc[4][8];
#pragma unroll
    for (int r = 0; r < 4; ++r)
#pragma unroll
        for (int c = 0; c < 8; ++c) acc[r][c] = (f32x4){0.f, 0.f, 0.f, 0.f};

    // A staging assignment: thread t -> row t>>2, k-eighth t&3 (8 floats)
    const int arow = tid >> 2, akq = tid & 3;
    const float* aptr = E + (size_t)(row0 + arow) * HID + akq * 8;

    for (int kc = 0; kc < NKC; ++kc) {
        // ---- stage A chunk (64x32 fp32 -> bf16 LDS) ----
        float4 a0 = *(const float4*)(aptr + kc * 32);
        float4 a1 = *(const float4*)(aptr + kc * 32 + 4);
        bf16x8 av;
        av[0] = f2bf(a0.x); av[1] = f2bf(a0.y); av[2] = f2bf(a0.z); av[3] = f2bf(a0.w);
        av[4] = f2bf(a1.x); av[5] = f2bf(a1.y); av[6] = f2bf(a1.z); av[7] = f2bf(a1.w);
        *(bf16x8*)&As[arow][akq * 8] = av;
        // ---- stage B chunk (32 KB) via global_load_lds width=16 ----
        const short* bsrc = Bp + (size_t)kc * 16384;
#pragma unroll
        for (int i = 0; i < 8; ++i) {
            int off = (i * 4 + wave) * 512;          // shorts; 1 KB per wave-issue
            async16(bsrc + off + lane * 8, &Bs[off]);
        }
        __syncthreads();
        // ---- compute: wave tile 64 rows x 128 cols ----
        bf16x8 fa[4];
#pragma unroll
        for (int r = 0; r < 4; ++r) fa[r] = *(bf16x8*)&As[r * 16 + l15][quad * 8];
#pragma unroll
        for (int c = 0; c < 8; ++c) {
            int nt = wave * 8 + c;
            bf16x8 fb = *(bf16x8*)&Bs[(nt * 64 + lane) * 8];
#pragma unroll
            for (int r = 0; r < 4; ++r)
                acc[r][c] = __builtin_amdgcn_mfma_f32_16x16x32_bf16(fa[r], fb, acc[r][c], 0, 0, 0);
        }
        __syncthreads();
    }

    // ---- epilogue a: score = sum_col tanh(acc + dproj[col]) * Wv[col] ----
    // acc[r][c][g] = enc_proj[row0 + r*16 + quad*4 + g][wave*128 + c*16 + l15]
    float part[4][4];
#pragma unroll
    for (int r = 0; r < 4; ++r)
#pragma unroll
        for (int g = 0; g < 4; ++g) part[r][g] = 0.f;
    const float* dp = dproj + (size_t)b * HID;
#pragma unroll
    for (int c = 0; c < 8; ++c) {
        int col = wave * 128 + c * 16 + l15;
        float dv = dp[col];
        float wv = Wv[col];
#pragma unroll
        for (int r = 0; r < 4; ++r)
#pragma unroll
            for (int g = 0; g < 4; ++g)
                part[r][g] += fast_tanh(acc[r][c][g] + dv) * wv;
    }
    // reduce across the 16 col-lanes (bits 0..3 of lane)
#pragma unroll
    for (int r = 0; r < 4; ++r)
#pragma unroll
        for (int g = 0; g < 4; ++g) {
            float v = part[r][g];
            v += __shfl_xor(v, 1); v += __shfl_xor(v, 2);
            v += __shfl_xor(v, 4); v += __shfl_xor(v, 8);
            part[r][g] = v;
        }
    if (l15 == 0) {
#pragma unroll
        for (int r = 0; r < 4; ++r)
#pragma unroll
            for (int g = 0; g < 4; ++g)
                fbuf[wave * 64 + r * 16 + quad * 4 + g] = part[r][g];
    }
    __syncthreads();
    if (tid < 64) {
        float s  = fbuf[tid] + fbuf[64 + tid] + fbuf[128 + tid] + fbuf[192 + tid];
        float pv = __expf(s);           // unnormalized; b_v cancels in softmax
        pbuf[tid] = pv;
        out[(size_t)NB * HID + row0 + tid] = pv;   // weights region, normalized later
        float t2 = pv;
        t2 += __shfl_xor(t2, 1);  t2 += __shfl_xor(t2, 2);  t2 += __shfl_xor(t2, 4);
        t2 += __shfl_xor(t2, 8);  t2 += __shfl_xor(t2, 16); t2 += __shfl_xor(t2, 32);
        if (tid == 0) atomicAdd(&sumacc[b], t2);
    }
    __syncthreads();

    // ---- epilogue b: partial context = sum_rows pv * E[row,:] (L2-hot re-read) ----
    const int hq = tid & 127, rh = tid >> 7;       // h = hq*4, rows rh*32..rh*32+31
    const float4* E4 = (const float4*)E;
    size_t cbase = (size_t)(row0 + rh * 32) * (HID / 4) + hq;
    float4 ca = {0.f, 0.f, 0.f, 0.f};
#pragma unroll 4
    for (int rr = 0; rr < 32; ++rr) {
        float w  = pbuf[rh * 32 + rr];
        float4 e = E4[cbase + (size_t)rr * (HID / 4)];
        ca.x += w * e.x; ca.y += w * e.y; ca.z += w * e.z; ca.w += w * e.w;
    }
    if (rh == 1) {
        fbuf[hq] = ca.x; fbuf[128 + hq] = ca.y; fbuf[256 + hq] = ca.z; fbuf[384 + hq] = ca.w;
    }
    __syncthreads();
    if (rh == 0) {
        ca.x += fbuf[hq]; ca.y += fbuf[128 + hq]; ca.z += fbuf[256 + hq]; ca.w += fbuf[384 + hq];
        float* cg = out + (size_t)b * HID + hq * 4;   // context region of d_out
        atomicAdd(cg + 0, ca.x); atomicAdd(cg + 1, ca.y);
        atomicAdd(cg + 2, ca.z); atomicAdd(cg + 3, ca.w);
    }
}

// ---------------------------------------------------------------------------
// K_finish: normalize in place: context /= sum, weights /= sum
// ---------------------------------------------------------------------------
__global__ void k_finish(float* __restrict__ out, const float* __restrict__ sumacc) {
    int b = blockIdx.x, t = threadIdx.x;
    float rs = 1.0f / sumacc[b];
    for (int i = t; i < HID; i += 256)
        out[(size_t)b * HID + i] *= rs;
    float* ow = out + (size_t)NB * HID + (size_t)b * SEQL;
    for (int i = t; i < SEQL; i += 256)
        ow[i] *= rs;
}

extern "C" void kernel_launch(void* const* d_in, const int* in_sizes, int n_in,
                              void* d_out, int out_size, void* d_ws, size_t ws_size,
                              hipStream_t stream) {
    const float* E   = (const float*)d_in[0];
    const float* dec = (const float*)d_in[1];
    const float* We  = (const float*)d_in[2];
    const float* be  = (const float*)d_in[3];
    const float* Wd  = (const float*)d_in[4];
    const float* bd  = (const float*)d_in[5];
    const float* Wv  = (const float*)d_in[6];
    // d_in[7] = b_v: uniform shift per score -> cancels in softmax
    float* out = (float*)d_out;
    char*  ws  = (char*)d_ws;
    short* Bp     = (short*)(ws + WS_BP);
    float* dproj  = (float*)(ws + WS_DPROJ);
    float* sumacc = (float*)(ws + WS_SUM);

    k_pre<<<704, 256, 0, stream>>>(We, Bp, dec, Wd, be, bd, dproj, out, sumacc);
    k_main<<<NBLK, 256, 0, stream>>>(E, Bp, dproj, Wv, out, sumacc);
    k_finish<<<NB, 256, 0, stream>>>(out, sumacc);
}

// Round 8
// 447.337 us; speedup vs baseline: 1.4496x; 1.0041x over previous
//
#include <hip/hip_runtime.h>
#include <hip/hip_bf16.h>

typedef __attribute__((ext_vector_type(8))) short bf16x8;
typedef __attribute__((ext_vector_type(4))) float f32x4;

#define HID 512
#define NB 32
#define SEQL 4096
#define BM 64
#define BK 64
#define NKC 8           // 512/64 k-chunks
#define NBLK 2048       // 131072 rows / 64

// workspace layout (bytes)
#define WS_BP    0              // packed bf16 W_enc: 512 KB
#define WS_DPROJ (512*1024)     // fp32 32x512: 64 KB
#define WS_SUM   (576*1024)     // fp32 32: 128 B

__device__ __forceinline__ short f2bf(float f) {
    unsigned u = __float_as_uint(f);
    unsigned r = (u + 0x7fffu + ((u >> 16) & 1u)) >> 16;   // RNE
    return (short)r;
}

__device__ __forceinline__ float fast_tanh(float x) {
    float e = __expf(2.0f * x);
    float r = __builtin_amdgcn_rcpf(e + 1.0f);
    return 1.0f - 2.0f * r;
}

__device__ __forceinline__ void async16(const void* g, void* l) {
    __builtin_amdgcn_global_load_lds((__attribute__((address_space(1))) void*)(g),
                                     (__attribute__((address_space(3))) void*)(l),
                                     16, 0, 0);
}

// ---------------------------------------------------------------------------
// K_pre (R3/R7 measured version): (a) W_enc pack fp32->bf16 B-frag layout
// [blk 0..127], (b) dproj GEMV 8-way h-parallel [blk 128..639],
// (c) zero ctx + sumacc [blk 640..703]
// ---------------------------------------------------------------------------
__global__ void k_pre(const float* __restrict__ We, short* __restrict__ Bp,
                      const float* __restrict__ dec, const float* __restrict__ Wd,
                      const float* __restrict__ be, const float* __restrict__ bd,
                      float* __restrict__ dproj, float* __restrict__ out,
                      float* __restrict__ sumacc) {
    const int blk = blockIdx.x, t = threadIdx.x;
    if (blk < 128) {
        // Bp[kc32][nt][lane][j] = We[kc32*32 + (lane>>4)*8 + j][nt*16 + (lane&15)]
        int tid  = blk * 256 + t;
        int lane = tid & 63;
        int nt   = (tid >> 6) & 31;
        int kc   = tid >> 11;
        int k0   = kc * 32 + (lane >> 4) * 8;
        int n    = nt * 16 + (lane & 15);
        bf16x8 v;
#pragma unroll
        for (int j = 0; j < 8; ++j) v[j] = f2bf(We[(size_t)(k0 + j) * HID + n]);
        *(bf16x8*)&Bp[(size_t)tid * 8] = v;
    } else if (blk < 640) {
        __shared__ float red[8][33];
        int bid2 = blk - 128;
        int b  = bid2 >> 4, kg = bid2 & 15;     // 32 batches x 16 k-groups
        int kl = t & 31,    hc = t >> 5;        // 32 k-cols x 8 h-chunks
        int k  = kg * 32 + kl;
        const float* dr = dec + (size_t)b * HID;
        float a = 0.f;
#pragma unroll 8
        for (int j = 0; j < 64; ++j) {
            int h = hc * 64 + j;
            a += dr[h] * Wd[(size_t)h * HID + k];
        }
        red[hc][kl] = a;
        __syncthreads();
        if (hc == 0) {
            float s = be[k] + bd[k];
#pragma unroll
            for (int c = 0; c < 8; ++c) s += red[c][kl];
            dproj[(size_t)b * HID + k] = s;
        }
    } else {
        int bz = blk - 640;
        out[bz * 256 + t] = 0.f;                // zero context region (16384 f32)
        if (bz == 0 && t < NB) sumacc[t] = 0.f;
    }
}

// ---------------------------------------------------------------------------
// K_main: R7 skeleton with BK=64 (8 iterations, 16 barriers vs 32):
// halves the count of barrier-drain latency exposures, amortizes each A-drain
// over 2x bytes. Per-iter: A 64x64 fp32->bf16 (4 float4/thread), B 64 KB via
// async16, 2 MFMA K-substeps of 32. Epilogues unchanged (R1-proven).
// ---------------------------------------------------------------------------
__global__ __launch_bounds__(256, 2)
void k_main(const float* __restrict__ E, const short* __restrict__ Bp,
            const float* __restrict__ dproj, const float* __restrict__ Wv,
            float* __restrict__ out, float* __restrict__ sumacc) {
    __shared__ short As[BM][BK + 8];   // 64 x 72 shorts = 9.2 KB (144 B row stride)
    __shared__ short Bs[BK * HID];     // 32768 shorts = 64 KB: two 32-k-chunks
    __shared__ float fbuf[640];
    __shared__ float pbuf[BM];

    const int tid  = threadIdx.x;
    const int wave = tid >> 6, lane = tid & 63;
    const int quad = lane >> 4, l15 = lane & 15;
    const int bid  = blockIdx.x;
    const int row0 = bid * BM;           // global row = b*4096 + s
    const int b    = bid >> 6;           // 64 blocks per batch

    f32x4 acc[4][8];
#pragma unroll
    for (int r = 0; r < 4; ++r)
#pragma unroll
        for (int c = 0; c < 8; ++c) acc[r][c] = (f32x4){0.f, 0.f, 0.f, 0.f};

    // A staging: thread t -> row t>>2, col-sixteenth t&3 (16 floats)
    const int arow = tid >> 2, akq = tid & 3;
    const float* aptr = E + (size_t)(row0 + arow) * HID + akq * 16;

    for (int kc = 0; kc < NKC; ++kc) {
        // ---- stage A chunk (64x64 fp32 -> bf16 LDS), 4-deep load pipeline ----
        float4 a0 = *(const float4*)(aptr + kc * 64);
        float4 a1 = *(const float4*)(aptr + kc * 64 + 4);
        float4 a2 = *(const float4*)(aptr + kc * 64 + 8);
        float4 a3 = *(const float4*)(aptr + kc * 64 + 12);
        // ---- stage B chunk (64 KB = two kc32 chunks) via global_load_lds ----
        const short* bsrc = Bp + (size_t)kc * 32768;
#pragma unroll
        for (int i = 0; i < 16; ++i) {
            int off = (i * 4 + wave) * 512;          // shorts; 1 KB per wave-issue
            async16(bsrc + off + lane * 8, &Bs[off]);
        }
        bf16x8 av;
        av[0] = f2bf(a0.x); av[1] = f2bf(a0.y); av[2] = f2bf(a0.z); av[3] = f2bf(a0.w);
        av[4] = f2bf(a1.x); av[5] = f2bf(a1.y); av[6] = f2bf(a1.z); av[7] = f2bf(a1.w);
        *(bf16x8*)&As[arow][akq * 16] = av;
        av[0] = f2bf(a2.x); av[1] = f2bf(a2.y); av[2] = f2bf(a2.z); av[3] = f2bf(a2.w);
        av[4] = f2bf(a3.x); av[5] = f2bf(a3.y); av[6] = f2bf(a3.z); av[7] = f2bf(a3.w);
        *(bf16x8*)&As[arow][akq * 16 + 8] = av;
        __syncthreads();
        // ---- compute: wave tile 64 rows x 128 cols, two K-substeps of 32 ----
#pragma unroll
        for (int ks = 0; ks < 2; ++ks) {
            bf16x8 fa[4];
#pragma unroll
            for (int r = 0; r < 4; ++r)
                fa[r] = *(bf16x8*)&As[r * 16 + l15][ks * 32 + quad * 8];
#pragma unroll
            for (int c = 0; c < 8; ++c) {
                int nt = wave * 8 + c;
                bf16x8 fb = *(bf16x8*)&Bs[ks * 16384 + (nt * 64 + lane) * 8];
#pragma unroll
                for (int r = 0; r < 4; ++r)
                    acc[r][c] = __builtin_amdgcn_mfma_f32_16x16x32_bf16(fa[r], fb, acc[r][c], 0, 0, 0);
            }
        }
        __syncthreads();
    }

    // ---- epilogue a: score = sum_col tanh(acc + dproj[col]) * Wv[col] ----
    // acc[r][c][g] = enc_proj[row0 + r*16 + quad*4 + g][wave*128 + c*16 + l15]
    float part[4][4];
#pragma unroll
    for (int r = 0; r < 4; ++r)
#pragma unroll
        for (int g = 0; g < 4; ++g) part[r][g] = 0.f;
    const float* dp = dproj + (size_t)b * HID;
#pragma unroll
    for (int c = 0; c < 8; ++c) {
        int col = wave * 128 + c * 16 + l15;
        float dv = dp[col];
        float wv = Wv[col];
#pragma unroll
        for (int r = 0; r < 4; ++r)
#pragma unroll
            for (int g = 0; g < 4; ++g)
                part[r][g] += fast_tanh(acc[r][c][g] + dv) * wv;
    }
    // reduce across the 16 col-lanes (bits 0..3 of lane)
#pragma unroll
    for (int r = 0; r < 4; ++r)
#pragma unroll
        for (int g = 0; g < 4; ++g) {
            float v = part[r][g];
            v += __shfl_xor(v, 1); v += __shfl_xor(v, 2);
            v += __shfl_xor(v, 4); v += __shfl_xor(v, 8);
            part[r][g] = v;
        }
    if (l15 == 0) {
#pragma unroll
        for (int r = 0; r < 4; ++r)
#pragma unroll
            for (int g = 0; g < 4; ++g)
                fbuf[wave * 64 + r * 16 + quad * 4 + g] = part[r][g];
    }
    __syncthreads();
    if (tid < 64) {
        float s  = fbuf[tid] + fbuf[64 + tid] + fbuf[128 + tid] + fbuf[192 + tid];
        float pv = __expf(s);           // unnormalized; b_v cancels in softmax
        pbuf[tid] = pv;
        out[(size_t)NB * HID + row0 + tid] = pv;   // weights region, normalized later
        float t2 = pv;
        t2 += __shfl_xor(t2, 1);  t2 += __shfl_xor(t2, 2);  t2 += __shfl_xor(t2, 4);
        t2 += __shfl_xor(t2, 8);  t2 += __shfl_xor(t2, 16); t2 += __shfl_xor(t2, 32);
        if (tid == 0) atomicAdd(&sumacc[b], t2);
    }
    __syncthreads();

    // ---- epilogue b: partial context = sum_rows pv * E[row,:] (L2-hot re-read) ----
    const int hq = tid & 127, rh = tid >> 7;       // h = hq*4, rows rh*32..rh*32+31
    const float4* E4 = (const float4*)E;
    size_t cbase = (size_t)(row0 + rh * 32) * (HID / 4) + hq;
    float4 ca = {0.f, 0.f, 0.f, 0.f};
#pragma unroll 4
    for (int rr = 0; rr < 32; ++rr) {
        float w  = pbuf[rh * 32 + rr];
        float4 e = E4[cbase + (size_t)rr * (HID / 4)];
        ca.x += w * e.x; ca.y += w * e.y; ca.z += w * e.z; ca.w += w * e.w;
    }
    if (rh == 1) {
        fbuf[hq] = ca.x; fbuf[128 + hq] = ca.y; fbuf[256 + hq] = ca.z; fbuf[384 + hq] = ca.w;
    }
    __syncthreads();
    if (rh == 0) {
        ca.x += fbuf[hq]; ca.y += fbuf[128 + hq]; ca.z += fbuf[256 + hq]; ca.w += fbuf[384 + hq];
        float* cg = out + (size_t)b * HID + hq * 4;   // context region of d_out
        atomicAdd(cg + 0, ca.x); atomicAdd(cg + 1, ca.y);
        atomicAdd(cg + 2, ca.z); atomicAdd(cg + 3, ca.w);
    }
}

// ---------------------------------------------------------------------------
// K_finish: normalize in place: context /= sum, weights /= sum
// ---------------------------------------------------------------------------
__global__ void k_finish(float* __restrict__ out, const float* __restrict__ sumacc) {
    int b = blockIdx.x, t = threadIdx.x;
    float rs = 1.0f / sumacc[b];
    for (int i = t; i < HID; i += 256)
        out[(size_t)b * HID + i] *= rs;
    float* ow = out + (size_t)NB * HID + (size_t)b * SEQL;
    for (int i = t; i < SEQL; i += 256)
        ow[i] *= rs;
}

extern "C" void kernel_launch(void* const* d_in, const int* in_sizes, int n_in,
                              void* d_out, int out_size, void* d_ws, size_t ws_size,
                              hipStream_t stream) {
    const float* E   = (const float*)d_in[0];
    const float* dec = (const float*)d_in[1];
    const float* We  = (const float*)d_in[2];
    const float* be  = (const float*)d_in[3];
    const float* Wd  = (const float*)d_in[4];
    const float* bd  = (const float*)d_in[5];
    const float* Wv  = (const float*)d_in[6];
    // d_in[7] = b_v: uniform shift per score -> cancels in softmax
    float* out = (float*)d_out;
    char*  ws  = (char*)d_ws;
    short* Bp     = (short*)(ws + WS_BP);
    float* dproj  = (float*)(ws + WS_DPROJ);
    float* sumacc = (float*)(ws + WS_SUM);

    k_pre<<<704, 256, 0, stream>>>(We, Bp, dec, Wd, be, bd, dproj, out, sumacc);
    k_main<<<NBLK, 256, 0, stream>>>(E, Bp, dproj, Wv, out, sumacc);
    k_finish<<<NB, 256, 0, stream>>>(out, sumacc);
}